// Round 9
// baseline (144.533 us; speedup 1.0000x reference)
//
#include <hip/hip_runtime.h>

#define TPB 256
#define WPB (TPB / 64)   // waves per block

// pitch-class bitmask of a 4-note row. Values are integer-valued floats in
// [0,128); x/12 == (x*683)>>13 exactly for 0<=x<=127 (24-bit mul safe).
__device__ __forceinline__ int pcmask(const float4 v) {
    int a = (int)v.x, b = (int)v.y, c = (int)v.z, d = (int)v.w;
    a -= 12 * (__mul24(a, 683) >> 13);
    b -= 12 * (__mul24(b, 683) >> 13);
    c -= 12 * (__mul24(c, 683) >> 13);
    d -= 12 * (__mul24(d, 683) >> 13);
    return (1 << a) | (1 << b) | (1 << c) | (1 << d);
}

// jaccard distance vs a 3-note template, via 16-entry LDS table [(p-1)*4 + inter]
__device__ __forceinline__ float jtabv(int m, int tmpl, const float* __restrict__ jt) {
    int p = __popc(m);
    int i = __popc(m & tmpl);
    return jt[((p - 1) << 2) + i];
}

// similarity via 80-entry LDS table [((p-1)*4 + (q-1))*5 + inter]
__device__ __forceinline__ float simval(int pm, int tm, const float* __restrict__ st) {
    int p = __popc(pm), q = __popc(tm), i = __popc(pm & tm);
    return st[(((p - 1) << 2) + (q - 1)) * 5 + i];
}

// Single worker dispatch: wave owns 128 contiguous rows. Tail: relaxed float
// atomicAdds to two LLC accumulators + a completion counter; the LAST block
// reads the final sums (atomicAdd(.,0) = coherent LLC read) and writes out[0].
// No acquire/release cache maintenance, no polling (R8 lesson).
__global__ void __launch_bounds__(TPB)
chord_loss_kernel(const float4* __restrict__ preds,
                  const float4* __restrict__ targs,
                  int T, int n_win, int nblk,
                  float* __restrict__ accS,   // poison-start -3e-13f: harmless
                  float* __restrict__ accP,
                  unsigned int* __restrict__ ctr,  // memset to 0 pre-launch
                  float* __restrict__ out) {
    __shared__ float jtab[16];
    __shared__ float stab[80];
    __shared__ float ls[WPB], lp[WPB];

    const int t    = threadIdx.x;
    const int lane = t & 63;
    const int wid  = t >> 6;
    const int base = (blockIdx.x * WPB + wid) * 128;
    const int i0   = base + lane;
    const int i1   = i0 + 64;

    // ---- issue ALL global loads first: latency overlaps table setup + barrier
    const int ic0 = min(i0, T - 1);
    const int ic1 = min(i1, T - 1);
    float4 pv0 = preds[ic0], tv0 = targs[ic0];
    float4 pv1 = preds[ic1], tv1 = targs[ic1];
    float4 pvx = preds[min(base + 128 + lane, T - 1)];   // only lanes 0-2 used

    // ---- LDS lookup tables (exact closed forms)
    if (t < 16) {                       // jaccard: [(p-1)*4 + inter]
        int p = (t >> 2) + 1, i = t & 3;
        jtab[t] = 1.0f - (float)i / ((float)(p + 3 - i) + 1e-8f);
    } else if (t < 96) {                // sim: [((p-1)*4+(q-1))*5 + inter]
        int u  = t - 16;
        int i  = u % 5, pq = u / 5;
        int p  = (pq >> 2) + 1, q = (pq & 3) + 1;
        const float eps = 1e-6f;
        float num = (float)i + eps * (float)(p + q) + 12.0f * eps * eps;
        float den = ((float)p + 12.0f * eps) * ((float)q + 12.0f * eps);
        stab[u] = fminf(fmaxf(num / den, 0.0f), 1.0f);
    }
    __syncthreads();

    int pm0 = pcmask(pv0), tm0 = pcmask(tv0);
    int pm1 = pcmask(pv1), tm1 = pcmask(tv1);
    int ext = pcmask(pvx);

    // boundary masks for rows base+128,129,130
    int e1 = __shfl(ext, 0), e2 = __shfl(ext, 1), e3 = __shfl(ext, 2);

    // half-0 neighbors: shfl_down in pm0; lanes 61-63 pull from pm1 rotates
    int a1 = __shfl_down(pm0, 1), a2 = __shfl_down(pm0, 2), a3 = __shfl_down(pm0, 3);
    int c1 = __shfl(pm1, (lane + 1) & 63);
    int c2 = __shfl(pm1, (lane + 2) & 63);
    int c3 = __shfl(pm1, (lane + 3) & 63);
    int m1 = (lane < 63) ? a1 : c1;
    int m2 = (lane < 62) ? a2 : c2;
    int m3 = (lane < 61) ? a3 : c3;

    // half-1 neighbors: reuse c rotates; wrap lanes take the e broadcasts
    int b1 = (lane == 63) ? e1 : c1;
    int b2 = (lane == 62) ? e1 : ((lane == 63) ? e2 : c2);
    int b3 = (lane == 61) ? e1 : ((lane == 62) ? e2 : ((lane == 63) ? e3 : c3));

    float s_acc = 0.0f, p_acc = 0.0f;
    if (i0 < T) s_acc += simval(pm0, tm0, stab);
    if (i1 < T) s_acc += simval(pm1, tm1, stab);

    if (i0 < n_win) {
        float maj = jtabv(pm0, 0x091, jtab) + jtabv(m1, 0x221, jtab) +
                    jtabv(m2,  0x884, jtab) + jtabv(m3, 0x091, jtab);
        float mn  = jtabv(pm0, 0x089, jtab) + jtabv(m1, 0x121, jtab) +
                    jtabv(m2,  0x484, jtab) + jtabv(m3, 0x089, jtab);
        p_acc += fminf(maj, mn);        // 0.25 factor applied at the end
    }
    if (i1 < n_win) {
        float maj = jtabv(pm1, 0x091, jtab) + jtabv(b1, 0x221, jtab) +
                    jtabv(b2,  0x884, jtab) + jtabv(b3, 0x091, jtab);
        float mn  = jtabv(pm1, 0x089, jtab) + jtabv(b1, 0x121, jtab) +
                    jtabv(b2,  0x484, jtab) + jtabv(b3, 0x089, jtab);
        p_acc += fminf(maj, mn);
    }

    // block reduction in float (block sums <= 1024; err << 2.6e-2 threshold)
    #pragma unroll
    for (int off = 32; off > 0; off >>= 1) {
        s_acc += __shfl_down(s_acc, off);
        p_acc += __shfl_down(p_acc, off);
    }
    if (lane == 0) { ls[wid] = s_acc; lp[wid] = p_acc; }
    __syncthreads();

    if (t == 0) {
        float bs = ls[0] + ls[1] + ls[2] + ls[3];
        float bp = lp[0] + lp[1] + lp[2] + lp[3];
        // relaxed device-scope adds (LLC RMW, no cache maintenance)
        atomicAdd(accS, bs);
        atomicAdd(accP, bp);
        // order the acc adds (write-acks) before the counter increment
        asm volatile("s_waitcnt vmcnt(0)" ::: "memory");
        unsigned int old = atomicAdd(ctr, 1u);
        if (old == (unsigned int)(nblk - 1)) {
            // last block: all acc adds are globally complete; coherent reads
            float st = atomicAdd(accS, 0.0f);
            float pt = atomicAdd(accP, 0.0f);
            out[0] = (float)((1.0 - (double)st / (double)T) +
                             0.5 * (0.25 * (double)pt / (double)n_win));
        }
    }
}

extern "C" void kernel_launch(void* const* d_in, const int* in_sizes, int n_in,
                              void* d_out, int out_size, void* d_ws, size_t ws_size,
                              hipStream_t stream) {
    const float4* preds = (const float4*)d_in[0];
    const float4* targs = (const float4*)d_in[1];
    float* out = (float*)d_out;

    unsigned int* ctr = (unsigned int*)d_ws;            // zeroed below
    float* accS       = (float*)((char*)d_ws + 4);      // 0xAA poison = -3e-13f,
    float* accP       = (float*)((char*)d_ws + 8);      // harmless as init

    int T      = in_sizes[0] / 4;          // rows
    int n_win  = T - 3;
    int nwaves = (T + 127) / 128;          // 128 rows per wave, single pass
    int nblk   = (nwaves + WPB - 1) / WPB;

    hipMemsetAsync(ctr, 0, sizeof(unsigned int), stream);
    chord_loss_kernel<<<nblk, TPB, 0, stream>>>(preds, targs, T, n_win, nblk,
                                                accS, accP, ctr, out);
}

// Round 10
// 77.092 us; speedup vs baseline: 1.8748x; 1.8748x over previous
//
#include <hip/hip_runtime.h>

#define TPB 256
#define WPB (TPB / 64)   // waves per block

// pitch-class bitmask of a 4-note row. Values are integer-valued floats in
// [0,128); x/12 == (x*683)>>13 exactly for 0<=x<=127 (24-bit mul safe).
__device__ __forceinline__ int pcmask(const float4 v) {
    int a = (int)v.x, b = (int)v.y, c = (int)v.z, d = (int)v.w;
    a -= 12 * (__mul24(a, 683) >> 13);
    b -= 12 * (__mul24(b, 683) >> 13);
    c -= 12 * (__mul24(c, 683) >> 13);
    d -= 12 * (__mul24(d, 683) >> 13);
    return (1 << a) | (1 << b) | (1 << c) | (1 << d);
}

// jaccard distance vs a 3-note template, via 16-entry LDS table [(p-1)*4 + inter]
__device__ __forceinline__ float jtabv(int m, int tmpl, const float* __restrict__ jt) {
    int p = __popc(m);
    int i = __popc(m & tmpl);
    return jt[((p - 1) << 2) + i];
}

// similarity via 80-entry LDS table [((p-1)*4 + (q-1))*5 + inter]
__device__ __forceinline__ float simval(int pm, int tm, const float* __restrict__ st) {
    int p = __popc(pm), q = __popc(tm), i = __popc(pm & tm);
    return st[(((p - 1) << 2) + (q - 1)) * 5 + i];
}

// Stage 1: wave owns 128 contiguous rows (lane -> base+lane, base+64+lane).
// Boundary rows base+128..130 loaded EARLY by lanes 0-2 and broadcast.
// Straight-line, no loop. One float2 partial per block, NO atomics (R9 lesson:
// same-address atomic RMWs cost ~13ns each serialized; slot stores are free).
__global__ void __launch_bounds__(TPB)
chord_partial_kernel(const float4* __restrict__ preds,
                     const float4* __restrict__ targs,
                     int T, int n_win,
                     float2* __restrict__ partials) {
    __shared__ float jtab[16];
    __shared__ float stab[80];
    __shared__ float ls[WPB], lp[WPB];

    const int t    = threadIdx.x;
    const int lane = t & 63;
    const int wid  = t >> 6;
    const int base = (blockIdx.x * WPB + wid) * 128;
    const int i0   = base + lane;
    const int i1   = i0 + 64;

    // ---- issue ALL global loads first: latency overlaps table setup + barrier
    const int ic0 = min(i0, T - 1);
    const int ic1 = min(i1, T - 1);
    float4 pv0 = preds[ic0], tv0 = targs[ic0];
    float4 pv1 = preds[ic1], tv1 = targs[ic1];
    float4 pvx = preds[min(base + 128 + lane, T - 1)];   // only lanes 0-2 used

    // ---- LDS lookup tables (exact closed forms)
    if (t < 16) {                       // jaccard: [(p-1)*4 + inter]
        int p = (t >> 2) + 1, i = t & 3;
        jtab[t] = 1.0f - (float)i / ((float)(p + 3 - i) + 1e-8f);
    } else if (t < 96) {                // sim: [((p-1)*4+(q-1))*5 + inter]
        int u  = t - 16;
        int i  = u % 5, pq = u / 5;
        int p  = (pq >> 2) + 1, q = (pq & 3) + 1;
        const float eps = 1e-6f;
        float num = (float)i + eps * (float)(p + q) + 12.0f * eps * eps;
        float den = ((float)p + 12.0f * eps) * ((float)q + 12.0f * eps);
        stab[u] = fminf(fmaxf(num / den, 0.0f), 1.0f);
    }
    __syncthreads();

    int pm0 = pcmask(pv0), tm0 = pcmask(tv0);
    int pm1 = pcmask(pv1), tm1 = pcmask(tv1);
    int ext = pcmask(pvx);

    // boundary masks for rows base+128,129,130
    int e1 = __shfl(ext, 0), e2 = __shfl(ext, 1), e3 = __shfl(ext, 2);

    // half-0 neighbors: shfl_down in pm0; lanes 61-63 pull from pm1 rotates
    int a1 = __shfl_down(pm0, 1), a2 = __shfl_down(pm0, 2), a3 = __shfl_down(pm0, 3);
    int c1 = __shfl(pm1, (lane + 1) & 63);
    int c2 = __shfl(pm1, (lane + 2) & 63);
    int c3 = __shfl(pm1, (lane + 3) & 63);
    int m1 = (lane < 63) ? a1 : c1;
    int m2 = (lane < 62) ? a2 : c2;
    int m3 = (lane < 61) ? a3 : c3;

    // half-1 neighbors: reuse c rotates; wrap lanes take the e broadcasts
    int b1 = (lane == 63) ? e1 : c1;
    int b2 = (lane == 62) ? e1 : ((lane == 63) ? e2 : c2);
    int b3 = (lane == 61) ? e1 : ((lane == 62) ? e2 : ((lane == 63) ? e3 : c3));

    float s_acc = 0.0f, p_acc = 0.0f;
    if (i0 < T) s_acc += simval(pm0, tm0, stab);
    if (i1 < T) s_acc += simval(pm1, tm1, stab);

    if (i0 < n_win) {
        float maj = jtabv(pm0, 0x091, jtab) + jtabv(m1, 0x221, jtab) +
                    jtabv(m2,  0x884, jtab) + jtabv(m3, 0x091, jtab);
        float mn  = jtabv(pm0, 0x089, jtab) + jtabv(m1, 0x121, jtab) +
                    jtabv(m2,  0x484, jtab) + jtabv(m3, 0x089, jtab);
        p_acc += fminf(maj, mn);        // 0.25 factor applied in finalize
    }
    if (i1 < n_win) {
        float maj = jtabv(pm1, 0x091, jtab) + jtabv(b1, 0x221, jtab) +
                    jtabv(b2,  0x884, jtab) + jtabv(b3, 0x091, jtab);
        float mn  = jtabv(pm1, 0x089, jtab) + jtabv(b1, 0x121, jtab) +
                    jtabv(b2,  0x484, jtab) + jtabv(b3, 0x089, jtab);
        p_acc += fminf(maj, mn);
    }

    // block reduction in float (block sums <= 1024; err << 2.6e-2 threshold)
    #pragma unroll
    for (int off = 32; off > 0; off >>= 1) {
        s_acc += __shfl_down(s_acc, off);
        p_acc += __shfl_down(p_acc, off);
    }
    if (lane == 0) { ls[wid] = s_acc; lp[wid] = p_acc; }
    __syncthreads();
    if (t == 0) partials[blockIdx.x] = make_float2(ls[0] + ls[1] + ls[2] + ls[3],
                                                   lp[0] + lp[1] + lp[2] + lp[3]);
}

// Stage 2: one block reduces the partials (double accum) and writes the scalar.
__global__ void __launch_bounds__(TPB)
chord_final_kernel(const float2* __restrict__ partials,
                   float* __restrict__ out, int T, int n_win, int nblk) {
    double s = 0.0, pg = 0.0;
    for (int t = threadIdx.x; t < nblk; t += TPB) {
        float2 v = partials[t];
        s  += (double)v.x;
        pg += (double)v.y;
    }
    #pragma unroll
    for (int off = 32; off > 0; off >>= 1) {
        s  += __shfl_down(s,  off);
        pg += __shfl_down(pg, off);
    }
    __shared__ double ls[TPB / 64], lp[TPB / 64];
    int wid = threadIdx.x >> 6, lane = threadIdx.x & 63;
    if (lane == 0) { ls[wid] = s; lp[wid] = pg; }
    __syncthreads();
    if (threadIdx.x == 0) {
        double st = 0.0, pt = 0.0;
        #pragma unroll
        for (int w = 0; w < TPB / 64; ++w) { st += ls[w]; pt += lp[w]; }
        out[0] = (float)((1.0 - st / (double)T) +
                         0.5 * (0.25 * pt / (double)n_win));
    }
}

extern "C" void kernel_launch(void* const* d_in, const int* in_sizes, int n_in,
                              void* d_out, int out_size, void* d_ws, size_t ws_size,
                              hipStream_t stream) {
    const float4* preds = (const float4*)d_in[0];
    const float4* targs = (const float4*)d_in[1];
    float* out = (float*)d_out;
    float2* partials = (float2*)d_ws;   // nblk float2 slots, fully overwritten

    int T      = in_sizes[0] / 4;          // rows
    int n_win  = T - 3;
    int nwaves = (T + 127) / 128;          // 128 rows per wave, single pass
    int nblk   = (nwaves + WPB - 1) / WPB;

    chord_partial_kernel<<<nblk, TPB, 0, stream>>>(preds, targs, T, n_win, partials);
    chord_final_kernel<<<1, TPB, 0, stream>>>(partials, out, T, n_win, nblk);
}